// Round 7
// baseline (1490.640 us; speedup 1.0000x reference)
//
#include <hip/hip_runtime.h>
#include <math.h>

#define WIDTH 192
#define KNN 12
#define G 64
#define NCELLS (G * G * G)
#define SMAX 8
#define BUILD_BLOCKS (NCELLS / 256)   // 1024

// ---------- sorted-12 list of (d,idx) packed as positive doubles ----------
#define CE(a, b) { double _lo = fmin(a, b); double _hi = fmax(a, b); a = _lo; b = _hi; }
#define INSERT12(key) { \
    b11 = fmin(b11, key); \
    CE(b10, b11); CE(b9, b10); CE(b8, b9); CE(b7, b8); CE(b6, b7); \
    CE(b5, b6);  CE(b4, b5); CE(b3, b4); CE(b2, b3); CE(b1, b2); CE(b0, b1); }
#define DECL12 double b0,b1,b2,b3,b4,b5,b6,b7,b8,b9,b10,b11
#define INIT12 { b0=__hiloint2double(0x7F7FFFFF,0);  b1=__hiloint2double(0x7F7FFFFF,1); \
    b2=__hiloint2double(0x7F7FFFFF,2);  b3=__hiloint2double(0x7F7FFFFF,3); \
    b4=__hiloint2double(0x7F7FFFFF,4);  b5=__hiloint2double(0x7F7FFFFF,5); \
    b6=__hiloint2double(0x7F7FFFFF,6);  b7=__hiloint2double(0x7F7FFFFF,7); \
    b8=__hiloint2double(0x7F7FFFFF,8);  b9=__hiloint2double(0x7F7FFFFF,9); \
    b10=__hiloint2double(0x7F7FFFFF,10); b11=__hiloint2double(0x7F7FFFFF,11); }

// butterfly merge stage (verified BM16 network, virtual +inf padding).
// m <= 16: merges stay within 32-lane groups (two queries per wave).
#define MERGE_STAGE(m) { \
    double pb11 = shflx_d(b11, m), pb10 = shflx_d(b10, m), pb9 = shflx_d(b9, m); \
    double pb8  = shflx_d(b8, m),  pb7  = shflx_d(b7, m),  pb6 = shflx_d(b6, m); \
    double pb5  = shflx_d(b5, m),  pb4  = shflx_d(b4, m),  pb3 = shflx_d(b3, m); \
    double pb2  = shflx_d(b2, m),  pb1  = shflx_d(b1, m),  pb0 = shflx_d(b0, m); \
    double c12 = pb3, c13 = pb2, c14 = pb1, c15 = pb0; \
    b4 = fmin(b4, pb11); b5 = fmin(b5, pb10); b6 = fmin(b6, pb9);  b7 = fmin(b7, pb8); \
    b8 = fmin(b8, pb7);  b9 = fmin(b9, pb6);  b10 = fmin(b10, pb5); b11 = fmin(b11, pb4); \
    CE(b0, b8);  CE(b1, b9);  CE(b2, b10); CE(b3, b11); \
    CE(b4, c12); CE(b5, c13); CE(b6, c14); CE(b7, c15); \
    CE(b0, b4);  CE(b1, b5);  CE(b2, b6);  CE(b3, b7); \
    CE(b8, c12); CE(b9, c13); CE(b10, c14); CE(b11, c15); \
    CE(b0, b2);  CE(b1, b3);  CE(b4, b6);  CE(b5, b7); \
    CE(b8, b10); CE(b9, b11); \
    CE(b0, b1);  CE(b2, b3);  CE(b4, b5);  CE(b6, b7); \
    CE(b8, b9);  CE(b10, b11); }

__device__ inline unsigned encf(float f) {
    unsigned u = __float_as_uint(f);
    return (u & 0x80000000u) ? ~u : (u | 0x80000000u);
}
__device__ inline float decf(unsigned u) {
    return (u & 0x80000000u) ? __uint_as_float(u & 0x7fffffffu) : __uint_as_float(~u);
}
__device__ inline int cellc(float v, float mn, float invh) {
    int c = (int)((v - mn) * invh);
    return min(max(c, 0), G - 1);
}
__device__ inline double shflx_d(double v, int m) {
    int lo = __shfl_xor(__double2loint(v), m, 64);
    int hi = __shfl_xor(__double2hiint(v), m, 64);
    return __hiloint2double(hi, lo);
}

// ---- software grid barrier (all blocks resident by launch-bounds math).
// Arrive: one RMW per block. Poll: non-RMW agent-scope load + s_sleep backoff
// (no same-address RMW storm). threadfence pair gives release/acquire; the
// fence runs on wave 0 but invalidates the CU's shared L1 for all block waves.
__device__ __forceinline__ void gbar(unsigned* c, unsigned target) {
    __syncthreads();
    if (threadIdx.x == 0) {
        __threadfence();
        atomicAdd(c, 1u);
        while (__hip_atomic_load(c, __ATOMIC_RELAXED, __HIP_MEMORY_SCOPE_AGENT)
               < target)
            __builtin_amdgcn_s_sleep(2);
        __threadfence();
    }
    __syncthreads();
}

// ---------------- fused grid build (7 dispatches -> 1) -----------------------
// 1024 blocks x 256 thr; __launch_bounds__(256,4) guarantees 4 blocks/CU
// (1024 co-resident). Phases: P0 zero/init -> P1 bbox + z-fold precompute
// -> P2 hist -> P3 block scan -> P4 cross-block prefix -> P5 scatter.
__global__ __launch_bounds__(256, 4) void build_kernel(
    const float* __restrict__ x, const float* __restrict__ z,
    const float* __restrict__ Wp, const float* __restrict__ bp,
    const float* __restrict__ Wg, const float* __restrict__ bgf,
    const float* __restrict__ Wb, const float* __restrict__ bbf,
    float* __restrict__ bias0, float* __restrict__ gammaB,
    float* __restrict__ betaB,
    unsigned* __restrict__ bbx, unsigned* __restrict__ counts,
    unsigned long long* __restrict__ rowmask, unsigned* __restrict__ offs,
    unsigned* __restrict__ bsums, unsigned* __restrict__ cursors,
    float4* __restrict__ sorted, unsigned* __restrict__ inv,
    unsigned* __restrict__ ctrs, int n)
{
    const int t = threadIdx.x, b = blockIdx.x;
    const int gid = b * 256 + t;
    const unsigned NB = gridDim.x;
    __shared__ unsigned su[256];
    __shared__ float zs[64];

    // P0: zero counts + rowmask, init bbox sentinels
    counts[gid] = 0u;
    if (gid < G * G) rowmask[gid] = 0ull;
    if (gid < 3) bbx[gid] = 0xFFFFFFFFu;
    else if (gid < 6) bbx[gid] = 0u;
    gbar(&ctrs[0], NB);

    // P1: bbox wave-reduce (blocks 0..n/256-1) + precompute (last block)
    if (gid < n) {
        unsigned emin[3], emax[3];
#pragma unroll
        for (int a = 0; a < 3; ++a) {
            unsigned e = encf(x[gid * 3 + a]); emin[a] = e; emax[a] = e;
        }
#pragma unroll
        for (int o = 32; o; o >>= 1) {
#pragma unroll
            for (int a = 0; a < 3; ++a) {
                emin[a] = min(emin[a], (unsigned)__shfl_xor((int)emin[a], o, 64));
                emax[a] = max(emax[a], (unsigned)__shfl_xor((int)emax[a], o, 64));
            }
        }
        if ((t & 63) == 0) {
#pragma unroll
            for (int a = 0; a < 3; ++a) {
                atomicMin(&bbx[a], emin[a]);
                atomicMax(&bbx[3 + a], emax[a]);
            }
        }
    }
    if (b == (int)NB - 1) {   // z-fold precompute (was its own kernel)
        if (t < 64) zs[t] = z[t];
        __syncthreads();
        if (t < WIDTH) {
            float acc = bp[t];
            for (int k = 0; k < 64; ++k) acc += zs[k] * Wp[(51 + k) * WIDTH + t];
            bias0[t] = acc;
            for (int l = 0; l < 4; ++l) {
                float g = bgf[l * WIDTH + t];
                float bv = bbf[l * WIDTH + t];
                for (int k = 0; k < 64; ++k) {
                    g  += zs[k] * Wg[(l * 64 + k) * WIDTH + t];
                    bv += zs[k] * Wb[(l * 64 + k) * WIDTH + t];
                }
                gammaB[l * WIDTH + t] = g;
                betaB[l * WIDTH + t] = bv;
            }
        }
    }
    gbar(&ctrs[1], NB);

    // P2: histogram + row occupancy masks
    if (gid < n) {
        float mnx = decf(bbx[0]), mny = decf(bbx[1]), mnz = decf(bbx[2]);
        float ivx = (float)G / (decf(bbx[3]) - mnx);
        float ivy = (float)G / (decf(bbx[4]) - mny);
        float ivz = (float)G / (decf(bbx[5]) - mnz);
        int cx = cellc(x[gid * 3 + 0], mnx, ivx);
        int cy = cellc(x[gid * 3 + 1], mny, ivy);
        int cz = cellc(x[gid * 3 + 2], mnz, ivz);
        atomicAdd(&counts[(cz * G + cy) * G + cx], 1u);
        atomicOr(&rowmask[cz * G + cy], 1ull << cx);
    }
    gbar(&ctrs[2], NB);

    // P3: per-block exclusive scan of 256 cells
    unsigned v = counts[gid];
    su[t] = v; __syncthreads();
    for (int off = 1; off < 256; off <<= 1) {
        unsigned xv = (t >= off) ? su[t - off] : 0u;
        __syncthreads();
        su[t] += xv;
        __syncthreads();
    }
    offs[gid] = su[t] - v;
    if (t == 255) bsums[b] = su[255];
    gbar(&ctrs[3], NB);

    // P4: add prefix of previous block sums
    {
        unsigned a = 0;
        for (int k = t; k < (int)NB; k += 256)
            if (k < b) a += bsums[k];
        __syncthreads();          // su reuse: P3 reads done block-wide
        su[t] = a; __syncthreads();
        for (int off = 128; off; off >>= 1) {
            if (t < off) su[t] += su[t + off];
            __syncthreads();
        }
        unsigned v2 = offs[gid] + su[0];
        offs[gid] = v2;
        cursors[gid] = v2;
        if (b == (int)NB - 1 && t == 255) offs[NCELLS] = (unsigned)n;
    }
    gbar(&ctrs[4], NB);

    // P5: scatter (builds sorted array + inverse permutation)
    if (gid < n) {
        float mnx = decf(bbx[0]), mny = decf(bbx[1]), mnz = decf(bbx[2]);
        float ivx = (float)G / (decf(bbx[3]) - mnx);
        float ivy = (float)G / (decf(bbx[4]) - mny);
        float ivz = (float)G / (decf(bbx[5]) - mnz);
        float x0 = x[gid * 3 + 0], x1 = x[gid * 3 + 1], x2 = x[gid * 3 + 2];
        int cx = cellc(x0, mnx, ivx);
        int cy = cellc(x1, mny, ivy);
        int cz = cellc(x2, mnz, ivz);
        unsigned pos = atomicAdd(&cursors[(cz * G + cy) * G + cx], 1u);
        sorted[pos] = make_float4(x0, x1, x2, __int_as_float(gid));
        inv[gid] = pos;
    }
}

// ---- grid kNN: TWO QUERIES PER WAVE (32 lanes each); fold chunk dispatch
//      (round-4 configuration — measured best; LPT sort regressed).
__global__ __launch_bounds__(64) void knn_grid_kernel(
    const float4* __restrict__ sorted, const unsigned* __restrict__ offs,
    const unsigned long long* __restrict__ rowmask,
    const unsigned* __restrict__ bb, const float* __restrict__ x,
    const unsigned* __restrict__ inv,
    unsigned short* __restrict__ knn, float* __restrict__ relf, int n)
{
    const int l = threadIdx.x;                  // 0..63
    const int l32 = l & 31;                     // lane within query group
    const int g32 = l >> 5;                     // which query (0/1)
    const int b = blockIdx.x;
    // chunked fold: chunk = 64 queries = 32 blocks; end slabs first
    const int nch = n >> 6;
    const int ch = b >> 5, posb = b & 31;
    const int fch = (ch & 1) ? (nch - 1 - (ch >> 1)) : (ch >> 1);
    const int p = fch * 64 + posb * 2 + g32;    // query = sorted index

    float mnx = decf(bb[0]), mny = decf(bb[1]), mnz = decf(bb[2]);
    float mxx = decf(bb[3]), mxy = decf(bb[4]), mxz = decf(bb[5]);
    float hx = (mxx - mnx) / G, hy = (mxy - mny) / G, hz = (mxz - mnz) / G;
    float ivx = (float)G / (mxx - mnx);
    float ivy = (float)G / (mxy - mny);
    float ivz = (float)G / (mxz - mnz);

    float4 q = sorted[p];
    float xi = q.x, yi = q.y, zi = q.z;
    int iorig = __float_as_int(q.w);
    float sqi = fmaf(zi, zi, fmaf(yi, yi, xi * xi));
    int cx = cellc(xi, mnx, ivx), cy = cellc(yi, mny, ivy), cz = cellc(zi, mnz, ivz);
    float fx = (xi - mnx) - cx * hx;
    float fy = (yi - mny) - cy * hy;
    float fz = (zi - mnz) - cz * hz;

    DECL12; INIT12;
    float worst = 3.402823466e+38f;    // this lane's 12th-best distance
    float worst_g = 3.402823466e+38f;  // group union upper bound
    int nc = 0;                        // this lane's insert count
    bool have12 = false;               // sticky: group has >=12 candidates

    auto groupMinWorst = [&]() -> float {
        float wm = worst;
        wm = fminf(wm, __shfl_xor(wm, 1, 64));
        wm = fminf(wm, __shfl_xor(wm, 2, 64));
        wm = fminf(wm, __shfl_xor(wm, 4, 64));
        wm = fminf(wm, __shfl_xor(wm, 8, 64));
        wm = fminf(wm, __shfl_xor(wm, 16, 64));
        return wm;
    };

    // 12th smallest of the 32 per-lane minima of this group (each a DISTINCT
    // candidate => valid upper bound on the group's union 12th distance).
    auto lane12Bound = [&]() -> float {
        float v = __int_as_float(__double2hiint(b0));
#pragma unroll
        for (int k = 2; k <= 32; k <<= 1) {
#pragma unroll
            for (int j = k >> 1; j >= 1; j >>= 1) {
                float pv = __shfl_xor(v, j, 64);
                bool dir = ((l32 & k) == 0);
                bool lower = ((l32 & j) == 0);
                float mn = fminf(v, pv), mx = fmaxf(v, pv);
                v = (lower == dir) ? mn : mx;
            }
        }
        return __shfl(v, (l & 32) | 11, 64);
    };

    // exact union 12th-best across the 32-lane group (on copies)
    auto groupUnionD12 = [&]() -> float {
        double c0=b0,c1=b1,c2=b2,c3=b3,c4=b4,c5=b5,c6=b6,c7=b7,c8=b8,c9=b9,c10=b10,c11=b11;
        {
            double b0=c0,b1=c1,b2=c2,b3=c3,b4=c4,b5=c5,b6=c6,b7=c7,b8=c8,b9=c9,b10=c10,b11=c11;
#pragma unroll
            for (int m = 1; m <= 16; m <<= 1) MERGE_STAGE(m)
            return __int_as_float(__double2hiint(b11));
        }
    };

    // serial scan with clamped prefetch (for rows owned by one lane)
    auto scanRange = [&](int c0, int c1) {
        unsigned j0 = offs[c0], j1 = offs[c1 + 1];
        if (j0 >= j1) return;
        float4 c = sorted[j0];
        for (unsigned t = j0; t < j1; ++t) {
            unsigned tn = (t + 1 < j1) ? t + 1 : t;
            float4 nx = sorted[tn];
            float sqj = fmaf(c.z, c.z, fmaf(c.y, c.y, c.x * c.x));
            float dot = fmaf(zi, c.z, fmaf(yi, c.y, xi * c.x));
            float d = fmaf(-2.0f, dot, sqi + sqj);
            int jg = __float_as_int(c.w);
            if (d <= fminf(worst, worst_g) && jg != iorig) {
                d = fmaxf(d, 0.0f);
                double key = __hiloint2double(__float_as_int(d), jg);
                INSERT12(key);
                worst = __int_as_float(__double2hiint(b11));
                ++nc;
            }
            c = nx;
        }
    };

    // strided scan: this lane takes candidates sub, sub+step, ... of the range
    auto scanStrided = [&](int c0, int c1, int sub, int step) {
        unsigned j0 = offs[c0], j1 = offs[c1 + 1];
        for (unsigned t = j0 + sub; t < j1; t += step) {
            float4 c = sorted[t];
            float sqj = fmaf(c.z, c.z, fmaf(c.y, c.y, c.x * c.x));
            float dot = fmaf(zi, c.z, fmaf(yi, c.y, xi * c.x));
            float d = fmaf(-2.0f, dot, sqi + sqj);
            int jg = __float_as_int(c.w);
            if (d <= fminf(worst, worst_g) && jg != iorig) {
                d = fmaxf(d, 0.0f);
                double key = __hiloint2double(__float_as_int(d), jg);
                INSERT12(key);
                worst = __int_as_float(__double2hiint(b11));
                ++nc;
            }
        }
    };

    // process one ring row (dz,dy known); sub/step partition within the row
    auto doRow = [&](int s, int dz, int dy, int sub, int step) {
        int zz = cz + dz, yy = cy + dy;
        if (zz < 0 || zz >= G || yy < 0 || yy >= G) return;
        int row = zz * G + yy;
        unsigned long long rm = rowmask[row];
        if (rm == 0ull) return;
        int rb = row * G;
        int adz = dz < 0 ? -dz : dz, ady = dy < 0 ? -dy : dy;
        if (adz == s || ady == s) {
            int x0 = max(cx - s, 0), x1 = min(cx + s, G - 1);
            unsigned long long msk =
                ((x1 == 63) ? ~0ull : ((1ull << (x1 + 1)) - 1ull)) &
                ~((1ull << x0) - 1ull);
            unsigned long long mm = rm & msk;
            if (mm) {
                int c0 = __ffsll((unsigned long long)mm) - 1;
                int c1 = 63 - __clzll((long long)mm);
                if (step == 1) scanRange(rb + c0, rb + c1);
                else           scanStrided(rb + c0, rb + c1, sub, step);
            }
        } else {
            int xm = cx - s, xp = cx + s;
            if (xm >= 0 && ((rm >> xm) & 1ull)) {
                if (step == 1) scanRange(rb + xm, rb + xm);
                else           scanStrided(rb + xm, rb + xm, sub, step);
            }
            if (xp < G && ((rm >> xp) & 1ull)) {
                if (step == 1) scanRange(rb + xp, rb + xp);
                else           scanStrided(rb + xp, rb + xp, sub, step);
            }
        }
    };

    // sticky gate: total distinct inserted candidates across group >= 12
    auto check12 = [&]() {
        if (!have12) {
            int ns = nc;
#pragma unroll
            for (int o = 1; o <= 16; o <<= 1) ns += __shfl_xor(ns, o, 64);
            have12 = (ns >= 12);
        }
    };

    bool done = false;
    for (int s = 0; s <= SMAX; ++s) {
        if (s > 0) {
            float bx = (s - 1) * hx + fminf(fx, hx - fx);
            float by = (s - 1) * hy + fminf(fy, hy - fy);
            float bz = (s - 1) * hz + fminf(fz, hz - fz);
            float bnd = fminf(bx, fminf(by, bz));
            float bnd2 = bnd * bnd;
            worst_g = fminf(worst_g, groupMinWorst());           // cheapest
            if (bnd2 > worst_g + 1e-4f) { done = true; break; }
            // lane12Bound finite only if >=12 lanes of group hold a candidate
            unsigned long long anyb =
                __ballot(__double2hiint(b0) != 0x7F7FFFFF);
            unsigned gm = (unsigned)(anyb >> (g32 << 5));
            if (__popc(gm) >= 12) {
                worst_g = fminf(worst_g, lane12Bound());         // cheap tight
                if (bnd2 > worst_g + 1e-4f) { done = true; break; }
            }
            if (s >= 2) {                                        // exact union
                check12();
                if (have12) {
                    worst_g = fminf(worst_g, groupUnionD12());
                    if (bnd2 > worst_g + 1e-4f) { done = true; break; }
                }
            }
        }
        if (s == 0) {
            int row = cz * G + cy;
            if ((rowmask[row] >> cx) & 1ull) {
                int rb = row * G;
                scanStrided(rb + cx, rb + cx, l32, 32);  // all 32 group lanes
            }
        } else {
            int w2 = 2 * s + 1;
            int nrows = w2 * w2;
            int lpr = 32 / nrows;                 // lanes per row (>1 for s=1)
            if (lpr > 1) {
                int r = l32 / lpr, sub = l32 - r * lpr;
                if (r < nrows) {
                    int dz = r / w2 - s, dy = r - (r / w2) * w2 - s;
                    doRow(s, dz, dy, sub, lpr);
                }
            } else {
                float rcp = 1.0f / (float)w2;
                for (int r = l32; r < nrows; r += 32) {
                    int qd = (int)((float)r * rcp);
                    int rem = r - qd * w2;
                    if (rem < 0) { qd--; rem += w2; }
                    else if (rem >= w2) { qd++; rem -= w2; }
                    doRow(s, qd - s, rem - s, 0, 1);
                }
            }
        }
    }
    if (!done) {  // final certification after shells 0..SMAX
        float bx = SMAX * hx + fminf(fx, hx - fx);
        float by = SMAX * hy + fminf(fy, hy - fy);
        float bz = SMAX * hz + fminf(fz, hz - fz);
        float bnd = fminf(bx, fminf(by, bz));
        float bnd2 = bnd * bnd;
        worst_g = fminf(worst_g, groupMinWorst());
        if (bnd2 > worst_g + 1e-4f) done = true;
        if (!done) {
            unsigned long long anyb =
                __ballot(__double2hiint(b0) != 0x7F7FFFFF);
            unsigned gm = (unsigned)(anyb >> (g32 << 5));
            if (__popc(gm) >= 12) {
                worst_g = fminf(worst_g, lane12Bound());
                if (bnd2 > worst_g + 1e-4f) done = true;
            }
        }
        if (!done) {
            check12();
            if (have12) {
                worst_g = fminf(worst_g, groupUnionD12());
                if (bnd2 > worst_g + 1e-4f) done = true;
            }
        }
    }
    if (!done) {
        // brute force: reset lists (avoid duplicate keys) but KEEP worst_g —
        // it is a valid upper bound on the true d12, so brute inserts fire
        // only for candidates inside the final radius.
        INIT12;
        worst = 3.402823466e+38f;
        for (int base = 0; base < n; base += 256) {
            float4 cc[8];
#pragma unroll
            for (int r = 0; r < 8; ++r) cc[r] = sorted[base + l32 + r * 32];
#pragma unroll
            for (int r = 0; r < 8; ++r) {
                float4 c = cc[r];
                float sqj = fmaf(c.z, c.z, fmaf(c.y, c.y, c.x * c.x));
                float dot = fmaf(zi, c.z, fmaf(yi, c.y, xi * c.x));
                float d = fmaf(-2.0f, dot, sqi + sqj);
                int jg = __float_as_int(c.w);
                if (d <= fminf(worst, worst_g) && jg != iorig) {
                    d = fmaxf(d, 0.0f);
                    double key = __hiloint2double(__float_as_int(d), jg);
                    INSERT12(key);
                    worst = __int_as_float(__double2hiint(b11));
                }
            }
        }
    }

    // ---- exact final merge of the group's 32 sorted-12 lists ----
#pragma unroll
    for (int m = 1; m <= 16; m <<= 1) MERGE_STAGE(m)

    if (l32 == 0) {   // lane 0 and lane 32 each write their query
        int idx[KNN];
        idx[0]=__double2loint(b0);  idx[1]=__double2loint(b1);  idx[2]=__double2loint(b2);
        idx[3]=__double2loint(b3);  idx[4]=__double2loint(b4);  idx[5]=__double2loint(b5);
        idx[6]=__double2loint(b6);  idx[7]=__double2loint(b7);  idx[8]=__double2loint(b8);
        idx[9]=__double2loint(b9);  idx[10]=__double2loint(b10); idx[11]=__double2loint(b11);

        float rx[KNN], ry[KNN], rz[KNN];
        float sx = 0.f, sy = 0.f, sz = 0.f;
#pragma unroll
        for (int s = 0; s < KNN; ++s) {
            int j = idx[s];                       // original index (tie-break key)
            knn[(size_t)p * KNN + s] = (unsigned short)inv[j];  // sorted position
            rx[s] = x[(size_t)j * 3 + 0] - xi;
            ry[s] = x[(size_t)j * 3 + 1] - yi;
            rz[s] = x[(size_t)j * 3 + 2] - zi;
            sx += rx[s]; sy += ry[s]; sz += rz[s];
        }
        float mx = sx / 12.0f, my = sy / 12.0f, mz = sz / 12.0f;
        float vx = 0.f, vy = 0.f, vz = 0.f;
#pragma unroll
        for (int s = 0; s < KNN; ++s) {
            float dx = rx[s] - mx, dy = ry[s] - my, dz = rz[s] - mz;
            vx += dx * dx; vy += dy * dy; vz += dz * dz;
        }
        float* rr = relf + (size_t)p * 8;
        rr[0] = mx; rr[1] = my; rr[2] = mz;
        rr[3] = sqrtf(vx / 12.0f); rr[4] = sqrtf(vy / 12.0f); rr[5] = sqrtf(vz / 12.0f);
        rr[6] = 0.0f; rr[7] = 0.0f;
    }
}

// ---------------- GEMM + silu (+FiLM): 64x192 tile, 4x12 micro, 256 thr ------
// Round-11 K-loop structure (BK=16, single buffer + register prefetch) —
// empirical best of 6 variants, do not restructure. Body is byte-identical
// to the round-6 kernels; only hoisted into a device function so the 5
// layers run in ONE kernel separated by grid barriers (launch gaps gone).
struct GemmSmem {
    float As[16][68];
    float Bs[16][196];
    float wouts[576];
};

template <int MODE>
__device__ __forceinline__ void gemm_layer(
    GemmSmem& sm, int m0, int tid,
    const float* __restrict__ A0, const unsigned short* __restrict__ knnp,
    const float* __restrict__ Rel, const float4* __restrict__ sorted4,
    const float* __restrict__ Bf0, const float* __restrict__ Bf1,
    const float* __restrict__ Bf2,
    const float* __restrict__ W, const float* __restrict__ bias,
    const float* __restrict__ gamma, const float* __restrict__ beta,
    const float* __restrict__ Wout, const float* __restrict__ bout,
    float* __restrict__ hout, float* __restrict__ fout)
{
    const int ty = tid >> 4, tx = tid & 15;
    const int arow = tid >> 2, akoff = (tid & 3) * 4;
    const int bk = tid >> 4,  bc = (tid & 15) * 12;

    float acc[4][12] = {};
    const int NCH = (MODE == 0) ? 4 : 24;

    if (MODE == 2) {
        for (int e = tid; e < 576; e += 256) sm.wouts[e] = Wout[e];
        // first __syncthreads in the main loop orders this before use
    }

    float qx = 0.f, qy = 0.f, qz = 0.f;
    if (MODE == 0) {
        float4 qq = sorted4[m0 + arow];
        qx = qq.x; qy = qq.y; qz = qq.z;
    }

    unsigned kf[6] = {0, 0, 0, 0, 0, 0};
    if (MODE != 0) {
        const unsigned* kp = (const unsigned*)(knnp + (size_t)(m0 + arow) * KNN);
#pragma unroll
        for (int w = 0; w < 6; ++w) kf[w] = kp[w];
    }

    auto loadA = [&](int ch) -> float4 {
        int k0 = ch * 16;
        if (MODE == 0) {
            // Fourier PE on the fly (identical expressions to old prep kernel)
            int c0 = k0 + akoff;          // c0 in {0,4,...,60}, 4 consecutive
            float v[4];
            if (c0 < 48) {
                int m = c0 >> 4, jb = c0 & 15;     // jb in {0,4,8,12}
                const float* B = (m == 0) ? Bf0 : (m == 1) ? Bf1 : Bf2;
                bool iscos = jb >= 8;
                int j0 = iscos ? jb - 8 : jb;
#pragma unroll
                for (int e = 0; e < 4; ++e) {
                    int j = j0 + e;
                    float arg = qx * B[j] + qy * B[8 + j] + qz * B[16 + j];
                    v[e] = iscos ? cosf(arg) : sinf(arg);
                }
            } else {
#pragma unroll
                for (int e = 0; e < 4; ++e) {
                    int c = c0 + e;
                    v[e] = (c == 48) ? qx : (c == 49) ? qy : (c == 50) ? qz : 0.0f;
                }
            }
            return make_float4(v[0], v[1], v[2], v[3]);
        } else if (k0 < 192) {
            return *(const float4*)&A0[(size_t)(m0 + arow) * 192 + k0 + akoff];
        } else {
            int c4 = (k0 - 192 + akoff) >> 2;
            const float4* h4 = (const float4*)A0;
            float4 s = make_float4(0.f, 0.f, 0.f, 0.f);
#pragma unroll
            for (int j = 0; j < KNN; ++j) {   // j compile-time: kf[] in regs
                unsigned idx = (j & 1) ? (kf[j >> 1] >> 16) : (kf[j >> 1] & 0xFFFFu);
                float4 v = h4[(size_t)idx * 48 + c4];
                s.x += v.x; s.y += v.y; s.z += v.z; s.w += v.w;
            }
            const float r = 1.0f / 12.0f;
            return make_float4(s.x * r, s.y * r, s.z * r, s.w * r);
        }
    };

    float4 ra = loadA(0);
    const float* wr0 = &W[(size_t)bk * 192 + bc];
    float4 rb0 = *(const float4*)&wr0[0];
    float4 rb1 = *(const float4*)&wr0[4];
    float4 rb2 = *(const float4*)&wr0[8];

    for (int ch = 0; ch < NCH; ++ch) {
        sm.As[akoff + 0][arow] = ra.x; sm.As[akoff + 1][arow] = ra.y;
        sm.As[akoff + 2][arow] = ra.z; sm.As[akoff + 3][arow] = ra.w;
        *(float4*)&sm.Bs[bk][bc + 0] = rb0;
        *(float4*)&sm.Bs[bk][bc + 4] = rb1;
        *(float4*)&sm.Bs[bk][bc + 8] = rb2;
        __syncthreads();
        if (ch + 1 < NCH) {
            ra = loadA(ch + 1);
            const float* wr = &W[(size_t)((ch + 1) * 16 + bk) * 192 + bc];
            rb0 = *(const float4*)&wr[0];
            rb1 = *(const float4*)&wr[4];
            rb2 = *(const float4*)&wr[8];
        }
#pragma unroll
        for (int k = 0; k < 16; ++k) {
            float4 a0 = *(const float4*)&sm.As[k][ty * 4];
            float av[4] = {a0.x, a0.y, a0.z, a0.w};
            float4 q0 = *(const float4*)&sm.Bs[k][tx * 12 + 0];
            float4 q1 = *(const float4*)&sm.Bs[k][tx * 12 + 4];
            float4 q2 = *(const float4*)&sm.Bs[k][tx * 12 + 8];
            float bv[12] = {q0.x, q0.y, q0.z, q0.w, q1.x, q1.y, q1.z, q1.w,
                            q2.x, q2.y, q2.z, q2.w};
#pragma unroll
            for (int a = 0; a < 4; ++a)
#pragma unroll
                for (int bcol = 0; bcol < 12; ++bcol)
                    acc[a][bcol] = fmaf(av[a], bv[bcol], acc[a][bcol]);
        }
        __syncthreads();
    }

    if (MODE != 0) {  // tail: k = 384..391 from relf8 (cols 6,7 zero)
        {
            int row = tid >> 2, cp = (tid & 3) * 2;
            float2 v = *(const float2*)&Rel[(size_t)(m0 + row) * 8 + cp];
            sm.As[cp + 0][row] = v.x; sm.As[cp + 1][row] = v.y;
        }
        {
            int k2 = tid >> 4, c = (tid & 15) * 12;
            if (k2 < 8) {
                int gk = 384 + k2; if (gk > 389) gk = 389;  // A rows 6,7 are 0
                const float* wr = &W[(size_t)gk * 192 + c];
                *(float4*)&sm.Bs[k2][c + 0] = *(const float4*)&wr[0];
                *(float4*)&sm.Bs[k2][c + 4] = *(const float4*)&wr[4];
                *(float4*)&sm.Bs[k2][c + 8] = *(const float4*)&wr[8];
            }
        }
        __syncthreads();
#pragma unroll
        for (int k = 0; k < 8; ++k) {
            float4 a0 = *(const float4*)&sm.As[k][ty * 4];
            float av[4] = {a0.x, a0.y, a0.z, a0.w};
            float4 q0 = *(const float4*)&sm.Bs[k][tx * 12 + 0];
            float4 q1 = *(const float4*)&sm.Bs[k][tx * 12 + 4];
            float4 q2 = *(const float4*)&sm.Bs[k][tx * 12 + 8];
            float bv[12] = {q0.x, q0.y, q0.z, q0.w, q1.x, q1.y, q1.z, q1.w,
                            q2.x, q2.y, q2.z, q2.w};
#pragma unroll
            for (int a = 0; a < 4; ++a)
#pragma unroll
                for (int bcol = 0; bcol < 12; ++bcol)
                    acc[a][bcol] = fmaf(av[a], bv[bcol], acc[a][bcol]);
        }
        __syncthreads();
    }

    float po[4][3] = {};
#pragma unroll
    for (int a = 0; a < 4; ++a) {
        int gi = m0 + ty * 4 + a;
        float res[12];
#pragma unroll
        for (int bcol = 0; bcol < 12; ++bcol) {
            int gc = tx * 12 + bcol;
            float v = acc[a][bcol] + bias[gc];
            float s = 1.0f / (1.0f + expf(-v));
            v = v * s;
            if (MODE != 0) v = v * gamma[gc] + beta[gc];
            res[bcol] = v;
        }
        if (MODE == 2) {
            // partial out-head dot: this thread owns cols tx*12..+11
#pragma unroll
            for (int e = 0; e < 12; ++e) {
                int c = tx * 12 + e;
                po[a][0] = fmaf(res[e], sm.wouts[c * 3 + 0], po[a][0]);
                po[a][1] = fmaf(res[e], sm.wouts[c * 3 + 1], po[a][1]);
                po[a][2] = fmaf(res[e], sm.wouts[c * 3 + 2], po[a][2]);
            }
        } else {
            float* orow = &hout[(size_t)gi * 192 + tx * 12];
            *(float4*)&orow[0] = make_float4(res[0], res[1], res[2], res[3]);
            *(float4*)&orow[4] = make_float4(res[4], res[5], res[6], res[7]);
            *(float4*)&orow[8] = make_float4(res[8], res[9], res[10], res[11]);
        }
    }

    if (MODE == 2) {
        // reduce partials across the 16 tx lanes (same-ty lanes are adjacent)
#pragma unroll
        for (int a = 0; a < 4; ++a)
#pragma unroll
            for (int j = 0; j < 3; ++j) {
                float v = po[a][j];
                v += __shfl_xor(v, 1, 64);
                v += __shfl_xor(v, 2, 64);
                v += __shfl_xor(v, 4, 64);
                v += __shfl_xor(v, 8, 64);
                po[a][j] = v;
            }
        if (tx == 0) {
#pragma unroll
            for (int a = 0; a < 4; ++a) {
                int gi = m0 + ty * 4 + a;
                int iorig = __float_as_int(sorted4[gi].w);
                fout[(size_t)iorig * 3 + 0] = (po[a][0] + bout[0]) * 0.01f;
                fout[(size_t)iorig * 3 + 1] = (po[a][1] + bout[1]) * 0.01f;
                fout[(size_t)iorig * 3 + 2] = (po[a][2] + bout[2]) * 0.01f;
            }
        }
    }
}

// all 5 layers in one kernel; 512 blocks x 256 thr; __launch_bounds__(256,2)
// guarantees >=2 blocks/CU (512 co-resident) for the grid barriers.
__global__ __launch_bounds__(256, 2) void mlp_kernel(
    const unsigned short* __restrict__ knnp, const float* __restrict__ Rel,
    const float4* __restrict__ sorted4,
    const float* __restrict__ B0, const float* __restrict__ B1,
    const float* __restrict__ B2,
    const float* __restrict__ Wp, const float* __restrict__ bias0,
    const float* __restrict__ Wl, const float* __restrict__ bl,
    const float* __restrict__ gammaB, const float* __restrict__ betaB,
    const float* __restrict__ Wout, const float* __restrict__ bout,
    float* __restrict__ hA, float* __restrict__ hB,
    float* __restrict__ fout, unsigned* __restrict__ ctrs)
{
    __shared__ GemmSmem sm;
    const int tid = threadIdx.x;
    const int m0 = blockIdx.x * 64;
    const unsigned NB = gridDim.x;

    gemm_layer<0>(sm, m0, tid, nullptr, nullptr, nullptr, sorted4, B0, B1, B2,
                  Wp, bias0, nullptr, nullptr, nullptr, nullptr, hA, nullptr);
    gbar(&ctrs[8], NB);

    float* hcur = hA;
    float* hnxt = hB;
    for (int li = 0; li < 3; ++li) {
        gemm_layer<1>(sm, m0, tid, hcur, knnp, Rel, nullptr,
                      nullptr, nullptr, nullptr,
                      Wl + (size_t)li * 390 * 192, bl + li * 192,
                      gammaB + li * 192, betaB + li * 192,
                      nullptr, nullptr, hnxt, nullptr);
        gbar(&ctrs[9 + li], NB);
        float* tp = hcur; hcur = hnxt; hnxt = tp;
    }
    gemm_layer<2>(sm, m0, tid, hcur, knnp, Rel, sorted4,
                  nullptr, nullptr, nullptr,
                  Wl + (size_t)3 * 390 * 192, bl + 3 * 192,
                  gammaB + 3 * 192, betaB + 3 * 192,
                  Wout, bout, nullptr, fout);
}

// ---------------- launch ------------------------------------------------------
extern "C" void kernel_launch(void* const* d_in, const int* in_sizes, int n_in,
                              void* d_out, int out_size, void* d_ws, size_t ws_size,
                              hipStream_t stream)
{
    const float* x    = (const float*)d_in[0];
    const float* z    = (const float*)d_in[1];
    const float* B0   = (const float*)d_in[2];
    const float* B1   = (const float*)d_in[3];
    const float* B2   = (const float*)d_in[4];
    const float* Wp   = (const float*)d_in[5];
    const float* bp   = (const float*)d_in[6];
    const float* Wl   = (const float*)d_in[7];
    const float* bl   = (const float*)d_in[8];
    const float* Wg   = (const float*)d_in[9];
    const float* bg   = (const float*)d_in[10];
    const float* Wb   = (const float*)d_in[11];
    const float* bb   = (const float*)d_in[12];
    const float* Wout = (const float*)d_in[13];
    const float* bout = (const float*)d_in[14];

    int n = in_sizes[0] / 3;  // 32768

    // workspace layout (float offsets)
    float* ws = (float*)d_ws;
    float* bias0  = ws;                    // 192
    float* gammaB = ws + 192;              // 768
    float* betaB  = ws + 960;              // 768
    unsigned* ctrs = (unsigned*)(ws + 1728);  // 16 u32 barrier counters
    size_t off = 1744;
    unsigned short* knn = (unsigned short*)(ws + off);  off += (size_t)n * 6;  // 12n u16
    float* relf = ws + off;                off += (size_t)n * 8;
    float4* sorted = (float4*)(ws + off);  off += (size_t)n * 4;  // persistent
    float* hA   = ws + off;                off += (size_t)n * 192;
    float* hB   = ws + off;                off += (size_t)n * 192;

    // grid scratch aliases inside hA (dead before mlp writes hA):
    unsigned* bbx     = (unsigned*)hA;              // 8 (6 used)
    unsigned* counts  = bbx + 8;                    // NCELLS
    unsigned* offsA   = counts + NCELLS;            // NCELLS + 1
    unsigned* cursors = offsA + NCELLS + 1;         // NCELLS
    unsigned* bsums   = cursors + NCELLS;           // BUILD_BLOCKS (1024)
    size_t gu = 8 + (size_t)NCELLS * 3 + 1 + BUILD_BLOCKS;
    gu = (gu + 1) & ~(size_t)1;                     // 8B align for u64
    unsigned long long* rowmask = (unsigned long long*)((unsigned*)hA + gu);  // G*G u64
    gu += (size_t)G * G * 2;
    unsigned* inv = (unsigned*)hA + gu;             // n u32 (orig -> sorted pos)

    hipMemsetAsync(ctrs, 0, 64, stream);
    build_kernel<<<BUILD_BLOCKS, 256, 0, stream>>>(
        x, z, Wp, bp, Wg, bg, Wb, bb, bias0, gammaB, betaB,
        bbx, counts, rowmask, offsA, bsums, cursors, sorted, inv, ctrs, n);
    // 64-thr blocks = 1 wave = 2 queries (32 lanes each); fold dispatch
    knn_grid_kernel<<<n / 2, 64, 0, stream>>>(sorted, offsA, rowmask, bbx, x,
                                              inv, knn, relf, n);
    // all 5 GEMM layers (PE-fused first layer, out-head-fused last) in one go
    mlp_kernel<<<n / 64, 256, 0, stream>>>(
        knn, relf, sorted, B0, B1, B2, Wp, bias0, Wl, bl, gammaB, betaB,
        Wout, bout, hA, hB, (float*)d_out, ctrs);
}

// Round 8
// 682.255 us; speedup vs baseline: 2.1849x; 2.1849x over previous
//
#include <hip/hip_runtime.h>
#include <math.h>

#define WIDTH 192
#define KNN 12
#define G 64
#define NCELLS (G * G * G)
#define SMAX 8

// ---------- sorted-12 list of (d,idx) packed as positive doubles ----------
#define CE(a, b) { double _lo = fmin(a, b); double _hi = fmax(a, b); a = _lo; b = _hi; }
#define INSERT12(key) { \
    b11 = fmin(b11, key); \
    CE(b10, b11); CE(b9, b10); CE(b8, b9); CE(b7, b8); CE(b6, b7); \
    CE(b5, b6);  CE(b4, b5); CE(b3, b4); CE(b2, b3); CE(b1, b2); CE(b0, b1); }
#define DECL12 double b0,b1,b2,b3,b4,b5,b6,b7,b8,b9,b10,b11
#define INIT12 { b0=__hiloint2double(0x7F7FFFFF,0);  b1=__hiloint2double(0x7F7FFFFF,1); \
    b2=__hiloint2double(0x7F7FFFFF,2);  b3=__hiloint2double(0x7F7FFFFF,3); \
    b4=__hiloint2double(0x7F7FFFFF,4);  b5=__hiloint2double(0x7F7FFFFF,5); \
    b6=__hiloint2double(0x7F7FFFFF,6);  b7=__hiloint2double(0x7F7FFFFF,7); \
    b8=__hiloint2double(0x7F7FFFFF,8);  b9=__hiloint2double(0x7F7FFFFF,9); \
    b10=__hiloint2double(0x7F7FFFFF,10); b11=__hiloint2double(0x7F7FFFFF,11); }

// butterfly merge stage (verified BM16 network, virtual +inf padding).
// m <= 16: merges stay within 32-lane groups (two queries per wave).
#define MERGE_STAGE(m) { \
    double pb11 = shflx_d(b11, m), pb10 = shflx_d(b10, m), pb9 = shflx_d(b9, m); \
    double pb8  = shflx_d(b8, m),  pb7  = shflx_d(b7, m),  pb6 = shflx_d(b6, m); \
    double pb5  = shflx_d(b5, m),  pb4  = shflx_d(b4, m),  pb3 = shflx_d(b3, m); \
    double pb2  = shflx_d(b2, m),  pb1  = shflx_d(b1, m),  pb0 = shflx_d(b0, m); \
    double c12 = pb3, c13 = pb2, c14 = pb1, c15 = pb0; \
    b4 = fmin(b4, pb11); b5 = fmin(b5, pb10); b6 = fmin(b6, pb9);  b7 = fmin(b7, pb8); \
    b8 = fmin(b8, pb7);  b9 = fmin(b9, pb6);  b10 = fmin(b10, pb5); b11 = fmin(b11, pb4); \
    CE(b0, b8);  CE(b1, b9);  CE(b2, b10); CE(b3, b11); \
    CE(b4, c12); CE(b5, c13); CE(b6, c14); CE(b7, c15); \
    CE(b0, b4);  CE(b1, b5);  CE(b2, b6);  CE(b3, b7); \
    CE(b8, c12); CE(b9, c13); CE(b10, c14); CE(b11, c15); \
    CE(b0, b2);  CE(b1, b3);  CE(b4, b6);  CE(b5, b7); \
    CE(b8, b10); CE(b9, b11); \
    CE(b0, b1);  CE(b2, b3);  CE(b4, b5);  CE(b6, b7); \
    CE(b8, b9);  CE(b10, b11); }

__device__ inline unsigned encf(float f) {
    unsigned u = __float_as_uint(f);
    return (u & 0x80000000u) ? ~u : (u | 0x80000000u);
}
__device__ inline float decf(unsigned u) {
    return (u & 0x80000000u) ? __uint_as_float(u & 0x7fffffffu) : __uint_as_float(~u);
}
__device__ inline int cellc(float v, float mn, float invh) {
    int c = (int)((v - mn) * invh);
    return min(max(c, 0), G - 1);
}
__device__ inline double shflx_d(double v, int m) {
    int lo = __shfl_xor(__double2loint(v), m, 64);
    int hi = __shfl_xor(__double2hiint(v), m, 64);
    return __hiloint2double(hi, lo);
}

// ---------------- precompute: fold z into biases -----------------------------
__global__ __launch_bounds__(256) void precompute_kernel(
    const float* __restrict__ z, const float* __restrict__ Wp, const float* __restrict__ bp,
    const float* __restrict__ Wg, const float* __restrict__ bg,
    const float* __restrict__ Wb, const float* __restrict__ bb,
    float* __restrict__ bias0, float* __restrict__ gammaB, float* __restrict__ betaB)
{
    __shared__ float zs[64];
    int t = threadIdx.x;
    if (t < 64) zs[t] = z[t];
    __syncthreads();
    if (t < WIDTH) {
        float acc = bp[t];
        for (int k = 0; k < 64; ++k) acc += zs[k] * Wp[(51 + k) * WIDTH + t];
        bias0[t] = acc;
        for (int l = 0; l < 4; ++l) {
            float g = bg[l * WIDTH + t];
            float b = bb[l * WIDTH + t];
            for (int k = 0; k < 64; ++k) {
                g += zs[k] * Wg[(l * 64 + k) * WIDTH + t];
                b += zs[k] * Wb[(l * 64 + k) * WIDTH + t];
            }
            gammaB[l * WIDTH + t] = g;
            betaB[l * WIDTH + t] = b;
        }
    }
}

// ---------------- grid build -------------------------------------------------
// fused: bbox-init + counts zero + rowmask zero (replaces 1 kernel + 2 memsets)
__global__ __launch_bounds__(256) void init_kernel(
    unsigned* __restrict__ bb, unsigned* __restrict__ counts,
    unsigned long long* __restrict__ rowmask)
{
    int i = blockIdx.x * 256 + threadIdx.x;
    if (i < 3) bb[i] = 0xFFFFFFFFu;
    else if (i < 6) bb[i] = 0u;
    counts[i] = 0u;                       // grid = NCELLS/256 blocks
    if (i < G * G) rowmask[i] = 0ull;
}

__global__ __launch_bounds__(256) void bbox_kernel(
    const float* __restrict__ x, unsigned* __restrict__ bb, int n)
{
    int i = blockIdx.x * 256 + threadIdx.x;
    unsigned emin[3], emax[3];
#pragma unroll
    for (int a = 0; a < 3; ++a) { unsigned e = encf(x[i * 3 + a]); emin[a] = e; emax[a] = e; }
#pragma unroll
    for (int o = 32; o; o >>= 1) {
#pragma unroll
        for (int a = 0; a < 3; ++a) {
            emin[a] = min(emin[a], (unsigned)__shfl_xor((int)emin[a], o, 64));
            emax[a] = max(emax[a], (unsigned)__shfl_xor((int)emax[a], o, 64));
        }
    }
    if ((threadIdx.x & 63) == 0) {
#pragma unroll
        for (int a = 0; a < 3; ++a) {
            atomicMin(&bb[a], emin[a]);
            atomicMax(&bb[3 + a], emax[a]);
        }
    }
}

__global__ __launch_bounds__(256) void hist_kernel(
    const float* __restrict__ x, const unsigned* __restrict__ bb,
    unsigned* __restrict__ counts, unsigned long long* __restrict__ rowmask, int n)
{
    int i = blockIdx.x * 256 + threadIdx.x;
    float mnx = decf(bb[0]), mny = decf(bb[1]), mnz = decf(bb[2]);
    float ivx = (float)G / (decf(bb[3]) - mnx);
    float ivy = (float)G / (decf(bb[4]) - mny);
    float ivz = (float)G / (decf(bb[5]) - mnz);
    int cx = cellc(x[i * 3 + 0], mnx, ivx);
    int cy = cellc(x[i * 3 + 1], mny, ivy);
    int cz = cellc(x[i * 3 + 2], mnz, ivz);
    atomicAdd(&counts[(cz * G + cy) * G + cx], 1u);
    atomicOr(&rowmask[cz * G + cy], 1ull << cx);
}

__global__ __launch_bounds__(256) void scan1_kernel(
    const unsigned* __restrict__ counts, unsigned* __restrict__ offs,
    unsigned* __restrict__ bsums)
{
    __shared__ unsigned s[256];
    int b = blockIdx.x, t = threadIdx.x;
    unsigned base = (unsigned)b * 1024 + t * 4;
    unsigned v[4], sum = 0;
#pragma unroll
    for (int k = 0; k < 4; ++k) { v[k] = counts[base + k]; sum += v[k]; }
    s[t] = sum; __syncthreads();
    for (int off = 1; off < 256; off <<= 1) {
        unsigned xv = (t >= off) ? s[t - off] : 0u;
        __syncthreads();
        s[t] += xv;
        __syncthreads();
    }
    unsigned excl = s[t] - sum;
    if (t == 255) bsums[b] = s[255];
    unsigned run = excl;
#pragma unroll
    for (int k = 0; k < 4; ++k) { offs[base + k] = run; run += v[k]; }
}

// scan3 with scan2 folded in: each block reduces raw bsums[0..b-1] itself
__global__ __launch_bounds__(256) void scan3_kernel(
    unsigned* __restrict__ offs, const unsigned* __restrict__ bsums,
    unsigned* __restrict__ cursors, int n)
{
    __shared__ unsigned s[256];
    int b = blockIdx.x, t = threadIdx.x;
    s[t] = (t < b) ? bsums[t] : 0u;
    __syncthreads();
    for (int off = 128; off; off >>= 1) {
        if (t < off) s[t] += s[t + off];
        __syncthreads();
    }
    unsigned add = s[0];
    unsigned base = (unsigned)b * 1024 + t * 4;
#pragma unroll
    for (int k = 0; k < 4; ++k) {
        unsigned v = offs[base + k] + add;
        offs[base + k] = v;
        cursors[base + k] = v;
    }
    if (b == 255 && t == 255) offs[NCELLS] = (unsigned)n;
}

// scatter also builds inverse permutation orig -> sorted position
__global__ __launch_bounds__(256) void scatter_kernel(
    const float* __restrict__ x, const unsigned* __restrict__ bb,
    unsigned* __restrict__ cursors, float4* __restrict__ sorted,
    unsigned* __restrict__ inv, int n)
{
    int i = blockIdx.x * 256 + threadIdx.x;
    float mnx = decf(bb[0]), mny = decf(bb[1]), mnz = decf(bb[2]);
    float ivx = (float)G / (decf(bb[3]) - mnx);
    float ivy = (float)G / (decf(bb[4]) - mny);
    float ivz = (float)G / (decf(bb[5]) - mnz);
    float x0 = x[i * 3 + 0], x1 = x[i * 3 + 1], x2 = x[i * 3 + 2];
    int cx = cellc(x0, mnx, ivx);
    int cy = cellc(x1, mny, ivy);
    int cz = cellc(x2, mnz, ivz);
    unsigned pos = atomicAdd(&cursors[(cz * G + cy) * G + cx], 1u);
    sorted[pos] = make_float4(x0, x1, x2, __int_as_float(i));
    inv[i] = pos;
}

// ---- grid kNN: TWO QUERIES PER WAVE (32 lanes each); fold chunk dispatch
//      (round-4 configuration — measured best; LPT sort regressed).
__global__ __launch_bounds__(64) void knn_grid_kernel(
    const float4* __restrict__ sorted, const unsigned* __restrict__ offs,
    const unsigned long long* __restrict__ rowmask,
    const unsigned* __restrict__ bb, const float* __restrict__ x,
    const unsigned* __restrict__ inv,
    unsigned short* __restrict__ knn, float* __restrict__ relf, int n)
{
    const int l = threadIdx.x;                  // 0..63
    const int l32 = l & 31;                     // lane within query group
    const int g32 = l >> 5;                     // which query (0/1)
    const int b = blockIdx.x;
    // chunked fold: chunk = 64 queries = 32 blocks; end slabs first
    const int nch = n >> 6;
    const int ch = b >> 5, posb = b & 31;
    const int fch = (ch & 1) ? (nch - 1 - (ch >> 1)) : (ch >> 1);
    const int p = fch * 64 + posb * 2 + g32;    // query = sorted index

    float mnx = decf(bb[0]), mny = decf(bb[1]), mnz = decf(bb[2]);
    float mxx = decf(bb[3]), mxy = decf(bb[4]), mxz = decf(bb[5]);
    float hx = (mxx - mnx) / G, hy = (mxy - mny) / G, hz = (mxz - mnz) / G;
    float ivx = (float)G / (mxx - mnx);
    float ivy = (float)G / (mxy - mny);
    float ivz = (float)G / (mxz - mnz);

    float4 q = sorted[p];
    float xi = q.x, yi = q.y, zi = q.z;
    int iorig = __float_as_int(q.w);
    float sqi = fmaf(zi, zi, fmaf(yi, yi, xi * xi));
    int cx = cellc(xi, mnx, ivx), cy = cellc(yi, mny, ivy), cz = cellc(zi, mnz, ivz);
    float fx = (xi - mnx) - cx * hx;
    float fy = (yi - mny) - cy * hy;
    float fz = (zi - mnz) - cz * hz;

    DECL12; INIT12;
    float worst = 3.402823466e+38f;    // this lane's 12th-best distance
    float worst_g = 3.402823466e+38f;  // group union upper bound
    int nc = 0;                        // this lane's insert count
    bool have12 = false;               // sticky: group has >=12 candidates

    auto groupMinWorst = [&]() -> float {
        float wm = worst;
        wm = fminf(wm, __shfl_xor(wm, 1, 64));
        wm = fminf(wm, __shfl_xor(wm, 2, 64));
        wm = fminf(wm, __shfl_xor(wm, 4, 64));
        wm = fminf(wm, __shfl_xor(wm, 8, 64));
        wm = fminf(wm, __shfl_xor(wm, 16, 64));
        return wm;
    };

    // 12th smallest of the 32 per-lane minima of this group (each a DISTINCT
    // candidate => valid upper bound on the group's union 12th distance).
    auto lane12Bound = [&]() -> float {
        float v = __int_as_float(__double2hiint(b0));
#pragma unroll
        for (int k = 2; k <= 32; k <<= 1) {
#pragma unroll
            for (int j = k >> 1; j >= 1; j >>= 1) {
                float pv = __shfl_xor(v, j, 64);
                bool dir = ((l32 & k) == 0);
                bool lower = ((l32 & j) == 0);
                float mn = fminf(v, pv), mx = fmaxf(v, pv);
                v = (lower == dir) ? mn : mx;
            }
        }
        return __shfl(v, (l & 32) | 11, 64);
    };

    // exact union 12th-best across the 32-lane group (on copies)
    auto groupUnionD12 = [&]() -> float {
        double c0=b0,c1=b1,c2=b2,c3=b3,c4=b4,c5=b5,c6=b6,c7=b7,c8=b8,c9=b9,c10=b10,c11=b11;
        {
            double b0=c0,b1=c1,b2=c2,b3=c3,b4=c4,b5=c5,b6=c6,b7=c7,b8=c8,b9=c9,b10=c10,b11=c11;
#pragma unroll
            for (int m = 1; m <= 16; m <<= 1) MERGE_STAGE(m)
            return __int_as_float(__double2hiint(b11));
        }
    };

    // serial scan with clamped prefetch (for rows owned by one lane)
    auto scanRange = [&](int c0, int c1) {
        unsigned j0 = offs[c0], j1 = offs[c1 + 1];
        if (j0 >= j1) return;
        float4 c = sorted[j0];
        for (unsigned t = j0; t < j1; ++t) {
            unsigned tn = (t + 1 < j1) ? t + 1 : t;
            float4 nx = sorted[tn];
            float sqj = fmaf(c.z, c.z, fmaf(c.y, c.y, c.x * c.x));
            float dot = fmaf(zi, c.z, fmaf(yi, c.y, xi * c.x));
            float d = fmaf(-2.0f, dot, sqi + sqj);
            int jg = __float_as_int(c.w);
            if (d <= fminf(worst, worst_g) && jg != iorig) {
                d = fmaxf(d, 0.0f);
                double key = __hiloint2double(__float_as_int(d), jg);
                INSERT12(key);
                worst = __int_as_float(__double2hiint(b11));
                ++nc;
            }
            c = nx;
        }
    };

    // strided scan: this lane takes candidates sub, sub+step, ... of the range
    auto scanStrided = [&](int c0, int c1, int sub, int step) {
        unsigned j0 = offs[c0], j1 = offs[c1 + 1];
        for (unsigned t = j0 + sub; t < j1; t += step) {
            float4 c = sorted[t];
            float sqj = fmaf(c.z, c.z, fmaf(c.y, c.y, c.x * c.x));
            float dot = fmaf(zi, c.z, fmaf(yi, c.y, xi * c.x));
            float d = fmaf(-2.0f, dot, sqi + sqj);
            int jg = __float_as_int(c.w);
            if (d <= fminf(worst, worst_g) && jg != iorig) {
                d = fmaxf(d, 0.0f);
                double key = __hiloint2double(__float_as_int(d), jg);
                INSERT12(key);
                worst = __int_as_float(__double2hiint(b11));
                ++nc;
            }
        }
    };

    // process one ring row (dz,dy known); sub/step partition within the row
    auto doRow = [&](int s, int dz, int dy, int sub, int step) {
        int zz = cz + dz, yy = cy + dy;
        if (zz < 0 || zz >= G || yy < 0 || yy >= G) return;
        int row = zz * G + yy;
        unsigned long long rm = rowmask[row];
        if (rm == 0ull) return;
        int rb = row * G;
        int adz = dz < 0 ? -dz : dz, ady = dy < 0 ? -dy : dy;
        if (adz == s || ady == s) {
            int x0 = max(cx - s, 0), x1 = min(cx + s, G - 1);
            unsigned long long msk =
                ((x1 == 63) ? ~0ull : ((1ull << (x1 + 1)) - 1ull)) &
                ~((1ull << x0) - 1ull);
            unsigned long long mm = rm & msk;
            if (mm) {
                int c0 = __ffsll((unsigned long long)mm) - 1;
                int c1 = 63 - __clzll((long long)mm);
                if (step == 1) scanRange(rb + c0, rb + c1);
                else           scanStrided(rb + c0, rb + c1, sub, step);
            }
        } else {
            int xm = cx - s, xp = cx + s;
            if (xm >= 0 && ((rm >> xm) & 1ull)) {
                if (step == 1) scanRange(rb + xm, rb + xm);
                else           scanStrided(rb + xm, rb + xm, sub, step);
            }
            if (xp < G && ((rm >> xp) & 1ull)) {
                if (step == 1) scanRange(rb + xp, rb + xp);
                else           scanStrided(rb + xp, rb + xp, sub, step);
            }
        }
    };

    // sticky gate: total distinct inserted candidates across group >= 12
    auto check12 = [&]() {
        if (!have12) {
            int ns = nc;
#pragma unroll
            for (int o = 1; o <= 16; o <<= 1) ns += __shfl_xor(ns, o, 64);
            have12 = (ns >= 12);
        }
    };

    bool done = false;
    for (int s = 0; s <= SMAX; ++s) {
        if (s > 0) {
            float bx = (s - 1) * hx + fminf(fx, hx - fx);
            float by = (s - 1) * hy + fminf(fy, hy - fy);
            float bz = (s - 1) * hz + fminf(fz, hz - fz);
            float bnd = fminf(bx, fminf(by, bz));
            float bnd2 = bnd * bnd;
            worst_g = fminf(worst_g, groupMinWorst());           // cheapest
            if (bnd2 > worst_g + 1e-4f) { done = true; break; }
            // lane12Bound finite only if >=12 lanes of group hold a candidate
            unsigned long long anyb =
                __ballot(__double2hiint(b0) != 0x7F7FFFFF);
            unsigned gm = (unsigned)(anyb >> (g32 << 5));
            if (__popc(gm) >= 12) {
                worst_g = fminf(worst_g, lane12Bound());         // cheap tight
                if (bnd2 > worst_g + 1e-4f) { done = true; break; }
            }
            if (s >= 2) {                                        // exact union
                check12();
                if (have12) {
                    worst_g = fminf(worst_g, groupUnionD12());
                    if (bnd2 > worst_g + 1e-4f) { done = true; break; }
                }
            }
        }
        if (s == 0) {
            int row = cz * G + cy;
            if ((rowmask[row] >> cx) & 1ull) {
                int rb = row * G;
                scanStrided(rb + cx, rb + cx, l32, 32);  // all 32 group lanes
            }
        } else {
            int w2 = 2 * s + 1;
            int nrows = w2 * w2;
            int lpr = 32 / nrows;                 // lanes per row (>1 for s=1)
            if (lpr > 1) {
                int r = l32 / lpr, sub = l32 - r * lpr;
                if (r < nrows) {
                    int dz = r / w2 - s, dy = r - (r / w2) * w2 - s;
                    doRow(s, dz, dy, sub, lpr);
                }
            } else {
                float rcp = 1.0f / (float)w2;
                for (int r = l32; r < nrows; r += 32) {
                    int qd = (int)((float)r * rcp);
                    int rem = r - qd * w2;
                    if (rem < 0) { qd--; rem += w2; }
                    else if (rem >= w2) { qd++; rem -= w2; }
                    doRow(s, qd - s, rem - s, 0, 1);
                }
            }
        }
    }
    if (!done) {  // final certification after shells 0..SMAX
        float bx = SMAX * hx + fminf(fx, hx - fx);
        float by = SMAX * hy + fminf(fy, hy - fy);
        float bz = SMAX * hz + fminf(fz, hz - fz);
        float bnd = fminf(bx, fminf(by, bz));
        float bnd2 = bnd * bnd;
        worst_g = fminf(worst_g, groupMinWorst());
        if (bnd2 > worst_g + 1e-4f) done = true;
        if (!done) {
            unsigned long long anyb =
                __ballot(__double2hiint(b0) != 0x7F7FFFFF);
            unsigned gm = (unsigned)(anyb >> (g32 << 5));
            if (__popc(gm) >= 12) {
                worst_g = fminf(worst_g, lane12Bound());
                if (bnd2 > worst_g + 1e-4f) done = true;
            }
        }
        if (!done) {
            check12();
            if (have12) {
                worst_g = fminf(worst_g, groupUnionD12());
                if (bnd2 > worst_g + 1e-4f) done = true;
            }
        }
    }
    if (!done) {
        // brute force: reset lists (avoid duplicate keys) but KEEP worst_g —
        // it is a valid upper bound on the true d12, so brute inserts fire
        // only for candidates inside the final radius.
        INIT12;
        worst = 3.402823466e+38f;
        for (int base = 0; base < n; base += 256) {
            float4 cc[8];
#pragma unroll
            for (int r = 0; r < 8; ++r) cc[r] = sorted[base + l32 + r * 32];
#pragma unroll
            for (int r = 0; r < 8; ++r) {
                float4 c = cc[r];
                float sqj = fmaf(c.z, c.z, fmaf(c.y, c.y, c.x * c.x));
                float dot = fmaf(zi, c.z, fmaf(yi, c.y, xi * c.x));
                float d = fmaf(-2.0f, dot, sqi + sqj);
                int jg = __float_as_int(c.w);
                if (d <= fminf(worst, worst_g) && jg != iorig) {
                    d = fmaxf(d, 0.0f);
                    double key = __hiloint2double(__float_as_int(d), jg);
                    INSERT12(key);
                    worst = __int_as_float(__double2hiint(b11));
                }
            }
        }
    }

    // ---- exact final merge of the group's 32 sorted-12 lists ----
#pragma unroll
    for (int m = 1; m <= 16; m <<= 1) MERGE_STAGE(m)

    if (l32 == 0) {   // lane 0 and lane 32 each write their query
        int idx[KNN];
        idx[0]=__double2loint(b0);  idx[1]=__double2loint(b1);  idx[2]=__double2loint(b2);
        idx[3]=__double2loint(b3);  idx[4]=__double2loint(b4);  idx[5]=__double2loint(b5);
        idx[6]=__double2loint(b6);  idx[7]=__double2loint(b7);  idx[8]=__double2loint(b8);
        idx[9]=__double2loint(b9);  idx[10]=__double2loint(b10); idx[11]=__double2loint(b11);

        float rx[KNN], ry[KNN], rz[KNN];
        float sx = 0.f, sy = 0.f, sz = 0.f;
#pragma unroll
        for (int s = 0; s < KNN; ++s) {
            int j = idx[s];                       // original index (tie-break key)
            knn[(size_t)p * KNN + s] = (unsigned short)inv[j];  // sorted position
            rx[s] = x[(size_t)j * 3 + 0] - xi;
            ry[s] = x[(size_t)j * 3 + 1] - yi;
            rz[s] = x[(size_t)j * 3 + 2] - zi;
            sx += rx[s]; sy += ry[s]; sz += rz[s];
        }
        float mx = sx / 12.0f, my = sy / 12.0f, mz = sz / 12.0f;
        float vx = 0.f, vy = 0.f, vz = 0.f;
#pragma unroll
        for (int s = 0; s < KNN; ++s) {
            float dx = rx[s] - mx, dy = ry[s] - my, dz = rz[s] - mz;
            vx += dx * dx; vy += dy * dy; vz += dz * dz;
        }
        float* rr = relf + (size_t)p * 8;
        rr[0] = mx; rr[1] = my; rr[2] = mz;
        rr[3] = sqrtf(vx / 12.0f); rr[4] = sqrtf(vy / 12.0f); rr[5] = sqrtf(vz / 12.0f);
        rr[6] = 0.0f; rr[7] = 0.0f;
    }
}

// ---------------- GEMM + silu (+FiLM): 64x192 tile, 4x12 micro, 256 thr ------
// Round-11 K-loop structure (BK=16, single buffer + register prefetch) —
// empirical best of 6 variants, do not restructure.
// MODE 0: first layer, Fourier-PE computed IN the A-staging (prep fused).
// MODE 1: mid layer (neighbor-mean A-staging + FiLM).
// MODE 2: last layer; output head fused into the epilogue (out = h@Wout).
// NEW (round 8): XCD-chunked blockIdx swizzle — each XCD owns a contiguous
// 64-block slab (4096 rows ~ 3.1 MB of h), so the h[knn] gather works out
// of its own 4 MiB L2 instead of fetching the whole 25 MB h from HBM.
// Bijective since gridDim.x = 512 ≡ 0 (mod 8). Results bit-identical.
template <int MODE>
__global__ __launch_bounds__(256) void gemm_silu_kernel(
    const float* __restrict__ A0, const unsigned short* __restrict__ knnp,
    const float* __restrict__ Rel, const float4* __restrict__ sorted4,
    const float* __restrict__ Bf0, const float* __restrict__ Bf1,
    const float* __restrict__ Bf2,
    const float* __restrict__ W, const float* __restrict__ bias,
    const float* __restrict__ gamma, const float* __restrict__ beta,
    const float* __restrict__ Wout, const float* __restrict__ bout,
    float* __restrict__ hout, float* __restrict__ fout)
{
    __shared__ float As[16][68];
    __shared__ float Bs[16][196];
    __shared__ float wouts[576];
    const int tid = threadIdx.x;
    const int ty = tid >> 4, tx = tid & 15;
    const int nwg = gridDim.x;                     // 512, % 8 == 0
    const int bsw = ((int)blockIdx.x & 7) * (nwg >> 3) + ((int)blockIdx.x >> 3);
    const int m0 = bsw * 64;
    const int arow = tid >> 2, akoff = (tid & 3) * 4;
    const int bk = tid >> 4,  bc = (tid & 15) * 12;

    float acc[4][12] = {};
    const int NCH = (MODE == 0) ? 4 : 24;

    if (MODE == 2) {
        for (int e = tid; e < 576; e += 256) wouts[e] = Wout[e];
        // first __syncthreads in the main loop orders this before use
    }

    float qx = 0.f, qy = 0.f, qz = 0.f;
    if (MODE == 0) {
        float4 qq = sorted4[m0 + arow];
        qx = qq.x; qy = qq.y; qz = qq.z;
    }

    unsigned kf[6] = {0, 0, 0, 0, 0, 0};
    if (MODE != 0) {
        const unsigned* kp = (const unsigned*)(knnp + (size_t)(m0 + arow) * KNN);
#pragma unroll
        for (int w = 0; w < 6; ++w) kf[w] = kp[w];
    }

    auto loadA = [&](int ch) -> float4 {
        int k0 = ch * 16;
        if (MODE == 0) {
            // Fourier PE on the fly (identical expressions to old prep kernel)
            int c0 = k0 + akoff;          // c0 in {0,4,...,60}, 4 consecutive
            float v[4];
            if (c0 < 48) {
                int m = c0 >> 4, jb = c0 & 15;     // jb in {0,4,8,12}
                const float* B = (m == 0) ? Bf0 : (m == 1) ? Bf1 : Bf2;
                bool iscos = jb >= 8;
                int j0 = iscos ? jb - 8 : jb;
#pragma unroll
                for (int e = 0; e < 4; ++e) {
                    int j = j0 + e;
                    float arg = qx * B[j] + qy * B[8 + j] + qz * B[16 + j];
                    v[e] = iscos ? cosf(arg) : sinf(arg);
                }
            } else {
#pragma unroll
                for (int e = 0; e < 4; ++e) {
                    int c = c0 + e;
                    v[e] = (c == 48) ? qx : (c == 49) ? qy : (c == 50) ? qz : 0.0f;
                }
            }
            return make_float4(v[0], v[1], v[2], v[3]);
        } else if (k0 < 192) {
            return *(const float4*)&A0[(size_t)(m0 + arow) * 192 + k0 + akoff];
        } else {
            int c4 = (k0 - 192 + akoff) >> 2;
            const float4* h4 = (const float4*)A0;
            float4 s = make_float4(0.f, 0.f, 0.f, 0.f);
#pragma unroll
            for (int j = 0; j < KNN; ++j) {   // j compile-time: kf[] in regs
                unsigned idx = (j & 1) ? (kf[j >> 1] >> 16) : (kf[j >> 1] & 0xFFFFu);
                float4 v = h4[(size_t)idx * 48 + c4];
                s.x += v.x; s.y += v.y; s.z += v.z; s.w += v.w;
            }
            const float r = 1.0f / 12.0f;
            return make_float4(s.x * r, s.y * r, s.z * r, s.w * r);
        }
    };

    float4 ra = loadA(0);
    const float* wr0 = &W[(size_t)bk * 192 + bc];
    float4 rb0 = *(const float4*)&wr0[0];
    float4 rb1 = *(const float4*)&wr0[4];
    float4 rb2 = *(const float4*)&wr0[8];

    for (int ch = 0; ch < NCH; ++ch) {
        As[akoff + 0][arow] = ra.x; As[akoff + 1][arow] = ra.y;
        As[akoff + 2][arow] = ra.z; As[akoff + 3][arow] = ra.w;
        *(float4*)&Bs[bk][bc + 0] = rb0;
        *(float4*)&Bs[bk][bc + 4] = rb1;
        *(float4*)&Bs[bk][bc + 8] = rb2;
        __syncthreads();
        if (ch + 1 < NCH) {
            ra = loadA(ch + 1);
            const float* wr = &W[(size_t)((ch + 1) * 16 + bk) * 192 + bc];
            rb0 = *(const float4*)&wr[0];
            rb1 = *(const float4*)&wr[4];
            rb2 = *(const float4*)&wr[8];
        }
#pragma unroll
        for (int k = 0; k < 16; ++k) {
            float4 a0 = *(const float4*)&As[k][ty * 4];
            float av[4] = {a0.x, a0.y, a0.z, a0.w};
            float4 q0 = *(const float4*)&Bs[k][tx * 12 + 0];
            float4 q1 = *(const float4*)&Bs[k][tx * 12 + 4];
            float4 q2 = *(const float4*)&Bs[k][tx * 12 + 8];
            float bv[12] = {q0.x, q0.y, q0.z, q0.w, q1.x, q1.y, q1.z, q1.w,
                            q2.x, q2.y, q2.z, q2.w};
#pragma unroll
            for (int a = 0; a < 4; ++a)
#pragma unroll
                for (int bcol = 0; bcol < 12; ++bcol)
                    acc[a][bcol] = fmaf(av[a], bv[bcol], acc[a][bcol]);
        }
        __syncthreads();
    }

    if (MODE != 0) {  // tail: k = 384..391 from relf8 (cols 6,7 zero)
        {
            int row = tid >> 2, cp = (tid & 3) * 2;
            float2 v = *(const float2*)&Rel[(size_t)(m0 + row) * 8 + cp];
            As[cp + 0][row] = v.x; As[cp + 1][row] = v.y;
        }
        {
            int k2 = tid >> 4, c = (tid & 15) * 12;
            if (k2 < 8) {
                int gk = 384 + k2; if (gk > 389) gk = 389;  // A rows 6,7 are 0
                const float* wr = &W[(size_t)gk * 192 + c];
                *(float4*)&Bs[k2][c + 0] = *(const float4*)&wr[0];
                *(float4*)&Bs[k2][c + 4] = *(const float4*)&wr[4];
                *(float4*)&Bs[k2][c + 8] = *(const float4*)&wr[8];
            }
        }
        __syncthreads();
#pragma unroll
        for (int k = 0; k < 8; ++k) {
            float4 a0 = *(const float4*)&As[k][ty * 4];
            float av[4] = {a0.x, a0.y, a0.z, a0.w};
            float4 q0 = *(const float4*)&Bs[k][tx * 12 + 0];
            float4 q1 = *(const float4*)&Bs[k][tx * 12 + 4];
            float4 q2 = *(const float4*)&Bs[k][tx * 12 + 8];
            float bv[12] = {q0.x, q0.y, q0.z, q0.w, q1.x, q1.y, q1.z, q1.w,
                            q2.x, q2.y, q2.z, q2.w};
#pragma unroll
            for (int a = 0; a < 4; ++a)
#pragma unroll
                for (int bcol = 0; bcol < 12; ++bcol)
                    acc[a][bcol] = fmaf(av[a], bv[bcol], acc[a][bcol]);
        }
        __syncthreads();
    }

    float po[4][3] = {};
#pragma unroll
    for (int a = 0; a < 4; ++a) {
        int gi = m0 + ty * 4 + a;
        float res[12];
#pragma unroll
        for (int bcol = 0; bcol < 12; ++bcol) {
            int gc = tx * 12 + bcol;
            float v = acc[a][bcol] + bias[gc];
            float s = 1.0f / (1.0f + expf(-v));
            v = v * s;
            if (MODE != 0) v = v * gamma[gc] + beta[gc];
            res[bcol] = v;
        }
        if (MODE == 2) {
            // partial out-head dot: this thread owns cols tx*12..+11
#pragma unroll
            for (int e = 0; e < 12; ++e) {
                int c = tx * 12 + e;
                po[a][0] = fmaf(res[e], wouts[c * 3 + 0], po[a][0]);
                po[a][1] = fmaf(res[e], wouts[c * 3 + 1], po[a][1]);
                po[a][2] = fmaf(res[e], wouts[c * 3 + 2], po[a][2]);
            }
        } else {
            float* orow = &hout[(size_t)gi * 192 + tx * 12];
            *(float4*)&orow[0] = make_float4(res[0], res[1], res[2], res[3]);
            *(float4*)&orow[4] = make_float4(res[4], res[5], res[6], res[7]);
            *(float4*)&orow[8] = make_float4(res[8], res[9], res[10], res[11]);
        }
    }

    if (MODE == 2) {
        // reduce partials across the 16 tx lanes (same-ty lanes are adjacent)
#pragma unroll
        for (int a = 0; a < 4; ++a)
#pragma unroll
            for (int j = 0; j < 3; ++j) {
                float v = po[a][j];
                v += __shfl_xor(v, 1, 64);
                v += __shfl_xor(v, 2, 64);
                v += __shfl_xor(v, 4, 64);
                v += __shfl_xor(v, 8, 64);
                po[a][j] = v;
            }
        if (tx == 0) {
#pragma unroll
            for (int a = 0; a < 4; ++a) {
                int gi = m0 + ty * 4 + a;
                int iorig = __float_as_int(sorted4[gi].w);
                fout[(size_t)iorig * 3 + 0] = (po[a][0] + bout[0]) * 0.01f;
                fout[(size_t)iorig * 3 + 1] = (po[a][1] + bout[1]) * 0.01f;
                fout[(size_t)iorig * 3 + 2] = (po[a][2] + bout[2]) * 0.01f;
            }
        }
    }
}

// ---------------- launch ------------------------------------------------------
extern "C" void kernel_launch(void* const* d_in, const int* in_sizes, int n_in,
                              void* d_out, int out_size, void* d_ws, size_t ws_size,
                              hipStream_t stream)
{
    const float* x    = (const float*)d_in[0];
    const float* z    = (const float*)d_in[1];
    const float* B0   = (const float*)d_in[2];
    const float* B1   = (const float*)d_in[3];
    const float* B2   = (const float*)d_in[4];
    const float* Wp   = (const float*)d_in[5];
    const float* bp   = (const float*)d_in[6];
    const float* Wl   = (const float*)d_in[7];
    const float* bl   = (const float*)d_in[8];
    const float* Wg   = (const float*)d_in[9];
    const float* bg   = (const float*)d_in[10];
    const float* Wb   = (const float*)d_in[11];
    const float* bb   = (const float*)d_in[12];
    const float* Wout = (const float*)d_in[13];
    const float* bout = (const float*)d_in[14];

    int n = in_sizes[0] / 3;  // 32768

    // workspace layout (float offsets)
    float* ws = (float*)d_ws;
    float* bias0  = ws;                    // 192
    float* gammaB = ws + 192;              // 768
    float* betaB  = ws + 960;              // 768
    size_t off = 1728;
    unsigned short* knn = (unsigned short*)(ws + off);  off += (size_t)n * 6;  // 12n u16
    float* relf = ws + off;                off += (size_t)n * 8;
    float4* sorted = (float4*)(ws + off);  off += (size_t)n * 4;  // persistent
    float* hA   = ws + off;                off += (size_t)n * 192;
    float* hB   = ws + off;                off += (size_t)n * 192;

    // grid scratch aliases inside hA (dead before gemm0 writes hA):
    unsigned* bbx     = (unsigned*)hA;              // 8 (6 used)
    unsigned* counts  = bbx + 8;                    // NCELLS
    unsigned* offsA   = counts + NCELLS;            // NCELLS + 1
    unsigned* cursors = offsA + NCELLS + 1;         // NCELLS
    unsigned* bsums   = cursors + NCELLS;           // 256
    size_t gu = 8 + (size_t)NCELLS * 3 + 1 + 256;
    gu = (gu + 1) & ~(size_t)1;                     // 8B align for u64
    unsigned long long* rowmask = (unsigned long long*)((unsigned*)hA + gu);  // G*G u64
    gu += (size_t)G * G * 2;
    unsigned* inv = (unsigned*)hA + gu;             // n u32 (orig -> sorted pos)

    init_kernel<<<NCELLS / 256, 256, 0, stream>>>(bbx, counts, rowmask);
    precompute_kernel<<<1, 256, 0, stream>>>(z, Wp, bp, Wg, bg, Wb, bb,
                                             bias0, gammaB, betaB);
    bbox_kernel<<<n / 256, 256, 0, stream>>>(x, bbx, n);
    hist_kernel<<<n / 256, 256, 0, stream>>>(x, bbx, counts, rowmask, n);
    scan1_kernel<<<NCELLS / 1024, 256, 0, stream>>>(counts, offsA, bsums);
    scan3_kernel<<<NCELLS / 1024, 256, 0, stream>>>(offsA, bsums, cursors, n);
    scatter_kernel<<<n / 256, 256, 0, stream>>>(x, bbx, cursors, sorted, inv, n);
    // 64-thr blocks = 1 wave = 2 queries (32 lanes each); fold dispatch
    knn_grid_kernel<<<n / 2, 64, 0, stream>>>(sorted, offsA, rowmask, bbx, x,
                                              inv, knn, relf, n);

    // first layer: PE computed in-staging (prep kernel + pe buffer gone)
    gemm_silu_kernel<0><<<n / 64, 256, 0, stream>>>(
        nullptr, nullptr, nullptr, sorted, B0, B1, B2,
        Wp, bias0, nullptr, nullptr, nullptr, nullptr, hA, nullptr);

    float* hcur = hA;
    float* hnxt = hB;
    for (int li = 0; li < 3; ++li) {
        gemm_silu_kernel<1><<<n / 64, 256, 0, stream>>>(
            hcur, knn, relf, nullptr, nullptr, nullptr, nullptr,
            Wl + (size_t)li * 390 * 192, bl + (size_t)li * 192,
            gammaB + (size_t)li * 192, betaB + (size_t)li * 192,
            nullptr, nullptr, hnxt, nullptr);
        float* t = hcur; hcur = hnxt; hnxt = t;
    }
    // last layer: output head fused (h never written back)
    gemm_silu_kernel<2><<<n / 64, 256, 0, stream>>>(
        hcur, knn, relf, sorted, nullptr, nullptr, nullptr,
        Wl + (size_t)3 * 390 * 192, bl + (size_t)3 * 192,
        gammaB + (size_t)3 * 192, betaB + (size_t)3 * 192,
        Wout, bout, nullptr, (float*)d_out);
}